// Round 4
// baseline (110.063 us; speedup 1.0000x reference)
//
#include <hip/hip_runtime.h>

#define PATCH_N 64
#define CH      4
#define PADDED  192
#define BATCH   512
#define PLANE   (PATCH_N * PATCH_N)      // 4096 floats per channel plane
#define THREADS 768                      // 12 waves: 3 xs-groups x 4 row-waves

// One block per batch; patch staged planar in exactly 64 KB LDS.
// Bilinear weights are per-channel constants (integer output grid), so the op
// is a constant-integer-shift 2x2 stencil. Each wave owns one 64-column chunk
// (xs = wid/4) and 48 rows (y = 4*it + wid%4). Column taps are pair-merged:
// read clamped pair (base, base+1) -> ds_read2_b32, with pair-remapped
// weights precomputed per lane at setup. Channels whose column footprint
// misses this wave's chunk are skipped wave-uniformly (ballot at setup).
// 768 thr + 64 KB LDS + low VGPR -> 2 blocks/CU: entire 512-block grid
// co-resident, no dispatch tail.
__global__ __launch_bounds__(THREADS, 6)
void reassemble_v4(const float* __restrict__ patches,
                   const float* __restrict__ positions,
                   float* __restrict__ out)
{
    __shared__ float lds[CH * PLANE];    // 64 KB, planar [c][y][x]

    const int b   = blockIdx.x;
    const int tid = threadIdx.x;

    // ---- stage: interleaved float4 -> planar LDS (stride-1 lanes, no conflicts)
    const float4* __restrict__ p4 =
        reinterpret_cast<const float4*>(patches + (size_t)b * PLANE * CH);
    for (int idx = tid; idx < PLANE; idx += THREADS) {
        const float4 v = p4[idx];
        lds[0 * PLANE + idx] = v.x;
        lds[1 * PLANE + idx] = v.y;
        lds[2 * PLANE + idx] = v.z;
        lds[3 * PLANE + idx] = v.w;
    }

    const int lane = tid & 63;
    const int wid  = tid >> 6;           // 0..11
    const int xs   = wid >> 2;           // 0..2 : this wave's column chunk
    const int rw   = wid & 3;            // 0..3 : row phase
    const int x    = xs * 64 + lane;

    // positions: (B,1,2,C) -> b*8 + j*4 + c ; j=0 dx, j=1 dy (block-uniform)
    const float* __restrict__ pos = positions + (size_t)b * 8;

    int   sy[CH];                        // integer row shift (uniform)
    float wy0c[CH], wy1c[CH];            // row frac weights (uniform)
    int   pidx[CH];                      // per-lane: plane idx of column pair base
    float w0p[CH], w1p[CH];              // per-lane: weights for pair (d0, d1)
    unsigned long long colOk[CH];        // wave-uniform: any nonzero col weight

#pragma unroll
    for (int c = 0; c < CH; ++c) {
        const float tx  = 64.0f + pos[c];        // dx
        const float sxf = ceilf(tx);
        const int   sx  = (int)sxf;
        const float wx1 = sxf - tx;
        const float wx0 = 1.0f - wx1;

        const float ty  = 64.0f + pos[CH + c];   // dy
        const float syf = ceilf(ty);
        sy[c]   = (int)syf;
        wy1c[c] = syf - ty;
        wy0c[c] = 1.0f - wy1c[c];

        const int j0 = x - sx;                   // left-tap column
        const float u0 = ((unsigned)j0       < 64u) ? wx0 : 0.0f;
        const float u1 = ((unsigned)(j0 + 1) < 64u) ? wx1 : 0.0f;
        const int base = min(max(j0, 0), 62);    // read pair (base, base+1)
        // remap tap weights onto the clamped pair:
        //  d0 = col base   : gets u0 if base==j0, u1 if base==j0+1, else 0
        //  d1 = col base+1 : gets u1 if base+1==j0+1, u0 if base+1==j0, else 0
        w0p[c] = (j0 == base)     ? u0 : ((j0 + 1 == base)     ? u1 : 0.0f);
        w1p[c] = (j0 + 1 == base + 1) ? u1 : ((j0 == base + 1) ? u0 : 0.0f);
        pidx[c] = c * PLANE + base;
        colOk[c] = __ballot((w0p[c] != 0.0f) || (w1p[c] != 0.0f));
    }

    __syncthreads();

    float* __restrict__ outb = out + (size_t)b * PADDED * PADDED + xs * 64 + lane;

#pragma unroll 4
    for (int it = 0; it < PADDED / 4; ++it) {    // 48 rows per wave
        const int y = it * 4 + rw;               // wave-uniform row
        float acc = 0.0f;

#pragma unroll
        for (int c = 0; c < CH; ++c) {
            const int iy0 = y - sy[c];
            if (colOk[c] == 0ull || (unsigned)(iy0 + 1) > 64u) continue;  // uniform skip

            const int   r0   = max(iy0, 0)      * PATCH_N;   // uniform row offsets
            const int   r1   = min(iy0 + 1, 63) * PATCH_N;
            const float wy0l = (iy0 >= 0) ? wy0c[c] : 0.0f;  // top-edge mask
            const float wy1l = (iy0 <= 62) ? wy1c[c] : 0.0f; // bottom-edge mask

            const float* __restrict__ pl = lds + pidx[c];
            const float d00 = pl[r0];
            const float d01 = pl[r0 + 1];
            const float d10 = pl[r1];
            const float d11 = pl[r1 + 1];

            float h0 = w0p[c] * d00;
            h0 = fmaf(w1p[c], d01, h0);
            float h1 = w0p[c] * d10;
            h1 = fmaf(w1p[c], d11, h1);
            acc = fmaf(wy0l, h0, acc);
            acc = fmaf(wy1l, h1, acc);
        }

        __builtin_nontemporal_store(acc, outb + y * PADDED);
    }
}

extern "C" void kernel_launch(void* const* d_in, const int* in_sizes, int n_in,
                              void* d_out, int out_size, void* d_ws, size_t ws_size,
                              hipStream_t stream) {
    const float* patches   = (const float*)d_in[0];
    const float* positions = (const float*)d_in[1];
    float* out = (float*)d_out;

    reassemble_v4<<<dim3(BATCH), THREADS, 0, stream>>>(patches, positions, out);
}

// Round 5
// 108.384 us; speedup vs baseline: 1.0155x; 1.0155x over previous
//
#include <hip/hip_runtime.h>

#define PATCH_N 64
#define CH      4
#define PADDED  192
#define BATCH   512
#define PLANE   (PATCH_N * PATCH_N)      // 4096 floats per channel plane
#define THREADS 768                      // 12 waves: 3 xs-groups x 4 row-phases

__device__ __forceinline__ int   rfl_i(int x)   { return __builtin_amdgcn_readfirstlane(x); }
__device__ __forceinline__ float rfl_f(float x) { return __int_as_float(__builtin_amdgcn_readfirstlane(__float_as_int(x))); }

// One block per batch; patch staged planar in 64 KB LDS. Bilinear weights are
// per-channel constants (integer output grid) -> constant-shift 2x2 stencil.
// R5 change: all wave-uniform quantities (channel shifts, row weights, row
// index, footprint flags) are forced into SGPRs via readfirstlane, so the
// per-(row,channel) skip test is SALU + s_cbranch and row offsets are SALU.
// Active-visit body: 2 v_add + 2 ds_read2_b32 + 6 mul/fma with SGPR weights.
__global__ __launch_bounds__(THREADS, 6)
void reassemble_v5(const float* __restrict__ patches,
                   const float* __restrict__ positions,
                   float* __restrict__ out)
{
    __shared__ float lds[CH * PLANE];    // 64 KB, planar [c][y][x]

    const int b   = blockIdx.x;
    const int tid = threadIdx.x;

    // ---- stage: interleaved float4 -> planar LDS (stride-1 lanes, conflict-free)
    const float4* __restrict__ p4 =
        reinterpret_cast<const float4*>(patches + (size_t)b * PLANE * CH);
    for (int idx = tid; idx < PLANE; idx += THREADS) {
        const float4 v = p4[idx];
        lds[0 * PLANE + idx] = v.x;
        lds[1 * PLANE + idx] = v.y;
        lds[2 * PLANE + idx] = v.z;
        lds[3 * PLANE + idx] = v.w;
    }

    const int lane = tid & 63;
    const int wid  = rfl_i(tid >> 6);    // wave-uniform -> SGPR
    const int xs   = wid >> 2;           // 0..2 : this wave's 64-column chunk
    const int rw   = wid & 3;            // 0..3 : row phase
    const int x    = xs * 64 + lane;

    // positions: (B,1,2,C) -> b*8 + j*4 + c ; j=0 dx, j=1 dy (block-uniform)
    const float* __restrict__ pos = positions + (size_t)b * 8;

    int   sy[CH];                        // SGPR: integer row shift
    float wy0c[CH], wy1c[CH];            // SGPR: row frac weights
    int   pb[CH];                        // VGPR: LDS byte addr of column-pair base
    float w0p[CH], w1p[CH];              // VGPR: pair-remapped column weights
    int   anyCol[CH];                    // SGPR: column footprint hits this chunk

#pragma unroll
    for (int c = 0; c < CH; ++c) {
        const float dxc = rfl_f(pos[c]);
        const float dyc = rfl_f(pos[CH + c]);

        const float tx  = 64.0f + dxc;
        const float sxf = ceilf(tx);
        const int   sx  = rfl_i((int)sxf);
        const float wx1 = rfl_f(sxf - tx);
        const float wx0 = 1.0f - wx1;

        const float ty  = 64.0f + dyc;
        const float syf = ceilf(ty);
        sy[c]   = rfl_i((int)syf);
        wy1c[c] = rfl_f(syf - ty);
        wy0c[c] = 1.0f - wy1c[c];

        const int j0 = x - sx;                   // left-tap column (per lane)
        const float u0 = ((unsigned)j0       < 64u) ? wx0 : 0.0f;
        const float u1 = ((unsigned)(j0 + 1) < 64u) ? wx1 : 0.0f;
        const int base = min(max(j0, 0), 62);    // clamped pair (base, base+1)
        // remap tap weights onto clamped pair; invalid taps get exact 0.0f
        w0p[c] = (j0 == base)         ? u0 : ((j0 + 1 == base) ? u1 : 0.0f);
        w1p[c] = (j0 + 1 == base + 1) ? u1 : ((j0 == base + 1) ? u0 : 0.0f);
        pb[c]  = (c * PLANE + base) * 4;
        anyCol[c] = (__ballot((w0p[c] != 0.0f) || (w1p[c] != 0.0f)) != 0ull) ? 1 : 0;
    }

    __syncthreads();

    float* __restrict__ outb = out + (size_t)b * PADDED * PADDED + xs * 64 + lane;

#pragma unroll 4
    for (int it = 0; it < PADDED / 4; ++it) {    // 48 rows per wave
        const int y = it * 4 + rw;               // SALU row index
        float acc = 0.0f;

#pragma unroll
        for (int c = 0; c < CH; ++c) {
            const int iy0 = y - sy[c];           // SALU
            if (!anyCol[c] || (unsigned)(iy0 + 1) > 64u) continue;  // s_cbranch skip

            const int r0b = max(iy0, 0)      << 8;   // row byte offset (64 cols * 4 B)
            const int r1b = min(iy0 + 1, 63) << 8;
            const float wy0l = (iy0 >= 0)  ? wy0c[c] : 0.0f;  // top-edge mask (SALU)
            const float wy1l = (iy0 <= 62) ? wy1c[c] : 0.0f;  // bottom-edge mask

            const float* a0 = (const float*)((const char*)lds + (pb[c] + r0b));
            const float* a1 = (const float*)((const char*)lds + (pb[c] + r1b));
            const float d00 = a0[0], d01 = a0[1];  // -> ds_read2_b32
            const float d10 = a1[0], d11 = a1[1];  // -> ds_read2_b32

            float h0 = w0p[c] * d00; h0 = fmaf(w1p[c], d01, h0);
            float h1 = w0p[c] * d10; h1 = fmaf(w1p[c], d11, h1);
            acc = fmaf(wy0l, h0, acc);
            acc = fmaf(wy1l, h1, acc);
        }

        __builtin_nontemporal_store(acc, outb + y * PADDED);
    }
}

extern "C" void kernel_launch(void* const* d_in, const int* in_sizes, int n_in,
                              void* d_out, int out_size, void* d_ws, size_t ws_size,
                              hipStream_t stream) {
    const float* patches   = (const float*)d_in[0];
    const float* positions = (const float*)d_in[1];
    float* out = (float*)d_out;

    reassemble_v5<<<dim3(BATCH), THREADS, 0, stream>>>(patches, positions, out);
}